// Round 1
// baseline (385.619 us; speedup 1.0000x reference)
//
#include <hip/hip_runtime.h>
#include <cstdint>

#define T_TOKENS 32768
#define D_MODEL  2048
#define N_EXP    64
#define BM       64
#define BK       64
#define CHUNKS   (D_MODEL / BK)   // 32
#define LDK      (BK + 8)         // 72 ushorts/row: stride 144B = 36 dwords (== 4 mod 32) -> 2-way banks (free), keeps 16B align

typedef short bf16x8 __attribute__((ext_vector_type(8)));
typedef unsigned short u16x8 __attribute__((ext_vector_type(8)));
typedef float f32x4 __attribute__((ext_vector_type(4)));

__device__ __forceinline__ unsigned short f2bf(float f) {
    union { float f; unsigned int u; } c; c.f = f;
    unsigned int u = c.u;
    u += 0x7fffu + ((u >> 16) & 1u);   // RNE
    return (unsigned short)(u >> 16);
}
__device__ __forceinline__ float bf2f(unsigned short h) {
    union { float f; unsigned int u; } c; c.u = ((unsigned int)h) << 16;
    return c.f;
}

// split 8 f32 into 3 bf16 terms each: f ~= h + m + l  (residual ~2^-27 |f|)
__device__ __forceinline__ void split3(const float4& a, const float4& b,
                                       u16x8& h, u16x8& m, u16x8& l) {
    float f[8] = {a.x, a.y, a.z, a.w, b.x, b.y, b.z, b.w};
#pragma unroll
    for (int i = 0; i < 8; ++i) {
        unsigned short hh = f2bf(f[i]);
        float r1 = f[i] - bf2f(hh);       // exact (two-term split)
        unsigned short mm = f2bf(r1);
        float r2 = r1 - bf2f(mm);
        unsigned short ll = f2bf(r2);
        h[i] = hh; m[i] = mm; l[i] = ll;
    }
}

__global__ __launch_bounds__(256, 2) void router_gemm(
    const float* __restrict__ x, const float* __restrict__ W,
    const float* __restrict__ b, float* __restrict__ logits)
{
    __shared__ unsigned short Ah[BM * LDK], Amid[BM * LDK], Alo[BM * LDK];
    __shared__ unsigned short Bh[N_EXP * LDK], Bmid[N_EXP * LDK], Blo[N_EXP * LDK];

    const int tid = threadIdx.x;
    const int t0  = blockIdx.x * BM;
    const int kq  = tid & 7;        // k-octet within row (k = kq*8)
    const int rid = tid >> 3;       // 0..31 (rows rid, rid+32)

    const float* xg = x + (long)(t0 + rid) * D_MODEL + kq * 8;
    const float* wg = W + (long)rid * D_MODEL + kq * 8;

    const int lane = tid & 63;
    const int w    = tid >> 6;          // wave id 0..3 -> token sub-tile
    const int ln   = lane & 15;
    const int kq8  = (lane >> 4) * 8;   // frag k-offset: contiguous-8 per lane
    const int aoff = (w * 16 + ln) * LDK;

    f32x4 accA[4], accB[4];
#pragma unroll
    for (int j = 0; j < 4; ++j) { accA[j] = (f32x4)(0.f); accB[j] = (f32x4)(0.f); }

    // prologue: load chunk 0 into regs
    float4 xr[2][2], wr[2][2];
#pragma unroll
    for (int p = 0; p < 2; ++p) {
        xr[p][0] = *(const float4*)(xg + (long)p * 32 * D_MODEL);
        xr[p][1] = *(const float4*)(xg + (long)p * 32 * D_MODEL + 4);
        wr[p][0] = *(const float4*)(wg + (long)p * 32 * D_MODEL);
        wr[p][1] = *(const float4*)(wg + (long)p * 32 * D_MODEL + 4);
    }

    for (int c = 0; c < CHUNKS; ++c) {
        // ---- convert current regs -> LDS (hi/mid/lo tiles) ----
#pragma unroll
        for (int p = 0; p < 2; ++p) {
            const int row = rid + p * 32;
            u16x8 h, m, l;
            split3(xr[p][0], xr[p][1], h, m, l);
            *(u16x8*)&Ah  [row * LDK + kq * 8] = h;
            *(u16x8*)&Amid[row * LDK + kq * 8] = m;
            *(u16x8*)&Alo [row * LDK + kq * 8] = l;
            split3(wr[p][0], wr[p][1], h, m, l);
            *(u16x8*)&Bh  [row * LDK + kq * 8] = h;
            *(u16x8*)&Bmid[row * LDK + kq * 8] = m;
            *(u16x8*)&Blo [row * LDK + kq * 8] = l;
        }
        // ---- prefetch next chunk (overlaps barrier + MFMA) ----
        if (c + 1 < CHUNKS) {
            const float* xn = xg + (c + 1) * BK;
            const float* wn = wg + (c + 1) * BK;
#pragma unroll
            for (int p = 0; p < 2; ++p) {
                xr[p][0] = *(const float4*)(xn + (long)p * 32 * D_MODEL);
                xr[p][1] = *(const float4*)(xn + (long)p * 32 * D_MODEL + 4);
                wr[p][0] = *(const float4*)(wn + (long)p * 32 * D_MODEL);
                wr[p][1] = *(const float4*)(wn + (long)p * 32 * D_MODEL + 4);
            }
        }
        __syncthreads();
        // ---- MFMA: 2 k-steps of 32; 6 split-products per expert-tile ----
#pragma unroll
        for (int ks = 0; ks < 2; ++ks) {
            const int ko = ks * 32 + kq8;
            bf16x8 ah = *(const bf16x8*)&Ah  [aoff + ko];
            bf16x8 am = *(const bf16x8*)&Amid[aoff + ko];
            bf16x8 al = *(const bf16x8*)&Alo [aoff + ko];
#pragma unroll
            for (int j = 0; j < 4; ++j) {
                const int boff = (j * 16 + ln) * LDK + ko;
                bf16x8 bh = *(const bf16x8*)&Bh  [boff];
                bf16x8 bm = *(const bf16x8*)&Bmid[boff];
                bf16x8 bl = *(const bf16x8*)&Blo [boff];
                accA[j] = __builtin_amdgcn_mfma_f32_16x16x32_bf16(ah, bh, accA[j], 0, 0, 0);
                accB[j] = __builtin_amdgcn_mfma_f32_16x16x32_bf16(am, bh, accB[j], 0, 0, 0);
                accB[j] = __builtin_amdgcn_mfma_f32_16x16x32_bf16(ah, bm, accB[j], 0, 0, 0);
                accB[j] = __builtin_amdgcn_mfma_f32_16x16x32_bf16(al, bh, accB[j], 0, 0, 0);
                accB[j] = __builtin_amdgcn_mfma_f32_16x16x32_bf16(am, bm, accB[j], 0, 0, 0);
                accB[j] = __builtin_amdgcn_mfma_f32_16x16x32_bf16(ah, bl, accB[j], 0, 0, 0);
            }
        }
        __syncthreads();
    }

    // ---- epilogue: + bias, / temperature, store logits ----
    float bias[4];
#pragma unroll
    for (int j = 0; j < 4; ++j) bias[j] = b[j * 16 + ln];
    const int trow = w * 16 + ((lane >> 4) << 2);   // C layout: row=(l>>4)*4+r, col=l&15
#pragma unroll
    for (int j = 0; j < 4; ++j) {
#pragma unroll
        for (int r = 0; r < 4; ++r) {
            float v = (accA[j][r] + accB[j][r] + bias[j]) / 0.1f;
            logits[(long)(t0 + trow + r) * N_EXP + j * 16 + ln] = v;
        }
    }
}

// top-8 of 64 per token; 8 lanes per token; jax tie-break (descending, lowest index first)
__global__ __launch_bounds__(256) void router_topk(
    const float* __restrict__ logits, float* __restrict__ probs, float* __restrict__ idxs)
{
    const int tid  = threadIdx.x;
    const int t    = blockIdx.x * 32 + (tid >> 3);
    const int s    = tid & 7;
    const int lane = tid & 63;

    const float* row = logits + (long)t * 64 + s * 8;
    float4 v0 = *(const float4*)row;
    float4 v1 = *(const float4*)(row + 4);
    float v[8] = {v0.x, v0.y, v0.z, v0.w, v1.x, v1.y, v1.z, v1.w};

    float sel_v = 0.f; int sel_i = 0;
#pragma unroll
    for (int p = 0; p < 8; ++p) {
        float bm = v[0]; int bi = s * 8;
#pragma unroll
        for (int i = 1; i < 8; ++i) {
            bool g = v[i] > bm;             // strict: keeps lowest index on ties
            bm = g ? v[i] : bm;
            bi = g ? s * 8 + i : bi;
        }
#pragma unroll
        for (int d = 1; d < 8; d <<= 1) {
            float om = __shfl_xor(bm, d);
            int   oi = __shfl_xor(bi, d);
            bool take = (om > bm) || (om == bm && oi < bi);
            bm = take ? om : bm;
            bi = take ? oi : bi;
        }
        if (s == p) { sel_v = bm; sel_i = bi; }
#pragma unroll
        for (int i = 0; i < 8; ++i)
            if (s * 8 + i == bi) v[i] = -__builtin_inff();   // consume (static indexing)
    }

    float mx = __shfl(sel_v, lane & ~7);     // pass-0 winner = row max
    float wgt = expf(sel_v - mx);
    float sum = wgt;
#pragma unroll
    for (int d = 1; d < 8; d <<= 1) sum += __shfl_xor(sum, d);

    probs[(long)t * 8 + s] = wgt / sum;      // full-softmax denominator cancels
    idxs [(long)t * 8 + s] = (float)sel_i;
}

extern "C" void kernel_launch(void* const* d_in, const int* in_sizes, int n_in,
                              void* d_out, int out_size, void* d_ws, size_t ws_size,
                              hipStream_t stream) {
    const float* x = (const float*)d_in[0];
    const float* W = (const float*)d_in[1];
    const float* b = (const float*)d_in[2];
    float* out    = (float*)d_out;
    float* logits = out;
    float* probs  = out + (long)T_TOKENS * N_EXP;
    float* idxs   = probs + (long)T_TOKENS * 8;

    router_gemm<<<dim3(T_TOKENS / BM), dim3(256), 0, stream>>>(x, W, b, logits);
    router_topk<<<dim3(T_TOKENS / 32), dim3(256), 0, stream>>>(logits, probs, idxs);
}